// Round 2
// baseline (317.462 us; speedup 1.0000x reference)
//
#include <hip/hip_runtime.h>

// Problem constants: B=8, L=64, D=768, H=12, d=64
#define DMODEL 768
#define NHEADS 12
#define RTOT   512           // B*L rows
#define BIW    9216          // NHEADS*DMODEL (per-(b,i) u/w row)

// ---------------------------------------------------------------------------
// 32x32-tile fp32 GEMM: dst[r, ct*32+c] = (sum_k src[r*ars + sk + k]*W[k, ct*32+c] + bias)*scale
// sk = ((ct*32)>>6)*scm selects per-head source slice when scm=768.
// grid = (RTOT/32=16, DMODEL/32=24), 256 threads
// ---------------------------------------------------------------------------
__global__ __launch_bounds__(256) void linear32(
    const float* __restrict__ src, int ars, int scm,
    const float* __restrict__ W, const float* __restrict__ bias,
    float* __restrict__ dst, int drs, float scale)
{
    __shared__ float At[32][64];   // 8 KB
    __shared__ float Bt[64][32];   // 8 KB
    const int rt = blockIdx.x, ct = blockIdx.y, t = threadIdx.x;
    const int sk = ((ct * 32) >> 6) * scm;
    const int c  = t & 31;
    const int rg = t >> 5;             // 8 groups x 4 rows
    float acc[4] = {0.f, 0.f, 0.f, 0.f};

    for (int kb = 0; kb < 12; ++kb) {
        if (kb) __syncthreads();
        #pragma unroll
        for (int kk = 0; kk < 2; ++kk) {
            int i4 = t + kk * 256;                 // 0..511
            int r = i4 >> 4, kq = i4 & 15;
            *(float4*)&At[r][kq * 4] =
                *(const float4*)&src[(size_t)(rt * 32 + r) * ars + sk + kb * 64 + kq * 4];
            int k = i4 >> 3, c4 = (i4 & 7) * 4;
            *(float4*)&Bt[k][c4] =
                *(const float4*)&W[(size_t)(kb * 64 + k) * DMODEL + ct * 32 + c4];
        }
        __syncthreads();
        #pragma unroll
        for (int kq = 0; kq < 16; ++kq) {
            float b0 = Bt[kq * 4 + 0][c], b1 = Bt[kq * 4 + 1][c];
            float b2 = Bt[kq * 4 + 2][c], b3 = Bt[kq * 4 + 3][c];
            #pragma unroll
            for (int i = 0; i < 4; ++i) {
                float4 a = *(const float4*)&At[rg * 4 + i][kq * 4];
                acc[i] += a.x * b0 + a.y * b1 + a.z * b2 + a.w * b3;
            }
        }
    }
    const float bb = bias[ct * 32 + c];
    #pragma unroll
    for (int i = 0; i < 4; ++i)
        dst[(size_t)(rt * 32 + rg * 4 + i) * drs + ct * 32 + c] = (acc[i] + bb) * scale;
}

// ---------------------------------------------------------------------------
// u[r, h, m] = sum_d Qp[r, h*64+d] * Wk[m, h*64+d];  cvec[r,h] = sum_d bk[h*64+d]*Qp[r,h*64+d]
// Batched per-head GEMM. grid = (16 row-tiles of 32, 12 m-tiles of 64, 12 heads), 256 thr
// ---------------------------------------------------------------------------
__global__ __launch_bounds__(256) void u_kernel(
    const float* __restrict__ qp, const float* __restrict__ Wk, const float* __restrict__ bk,
    float* __restrict__ u, float* __restrict__ cvec)
{
    __shared__ float Qt[32][64];    // 8 KB
    __shared__ float Bt[64][65];    // 16.25 KB (pad 65 -> conflict-free b32 row reads)
    const int rt = blockIdx.x, mt = blockIdx.y, h = blockIdx.z, t = threadIdx.x;

    #pragma unroll
    for (int kk = 0; kk < 2; ++kk) {
        int i4 = t + kk * 256;                  // 0..511
        int r = i4 >> 4, dq = i4 & 15;
        *(float4*)&Qt[r][dq * 4] =
            *(const float4*)&qp[(size_t)(rt * 32 + r) * DMODEL + h * 64 + dq * 4];
    }
    #pragma unroll
    for (int kk = 0; kk < 4; ++kk) {
        int i4 = t + kk * 256;                  // 0..1023
        int m = i4 >> 4, dq = i4 & 15;
        float4 v = *(const float4*)&Wk[(size_t)(mt * 64 + m) * DMODEL + h * 64 + dq * 4];
        Bt[m][dq * 4 + 0] = v.x; Bt[m][dq * 4 + 1] = v.y;
        Bt[m][dq * 4 + 2] = v.z; Bt[m][dq * 4 + 3] = v.w;
    }
    __syncthreads();

    const int c = t & 63, rg = t >> 6;          // c = m-col, rows rg*8..+8
    float acc[8] = {0.f,0.f,0.f,0.f,0.f,0.f,0.f,0.f};
    #pragma unroll
    for (int dq = 0; dq < 16; ++dq) {
        float b0 = Bt[c][dq * 4 + 0], b1 = Bt[c][dq * 4 + 1];
        float b2 = Bt[c][dq * 4 + 2], b3 = Bt[c][dq * 4 + 3];
        #pragma unroll
        for (int i = 0; i < 8; ++i) {
            float4 a = *(const float4*)&Qt[rg * 8 + i][dq * 4];
            acc[i] += a.x * b0 + a.y * b1 + a.z * b2 + a.w * b3;
        }
    }
    #pragma unroll
    for (int i = 0; i < 8; ++i)
        u[(size_t)(rt * 32 + rg * 8 + i) * BIW + h * DMODEL + mt * 64 + c] = acc[i];

    if (mt == 0 && t < 32) {
        float s = 0.f;
        for (int d = 0; d < 64; ++d) s += bk[h * 64 + d] * Qt[t][d];
        cvec[(rt * 32 + t) * NHEADS + h] = s;
    }
}

// ---------------------------------------------------------------------------
// Core: per (b,i) block, 512 threads. scores -> softmax -> w = attn^T * value
// u is read directly from global (wave-uniform broadcast addresses).
// ---------------------------------------------------------------------------
__global__ __launch_bounds__(512, 4) void attn_core(
    const float* __restrict__ key, const float* __restrict__ value, const float* __restrict__ mask,
    const float* __restrict__ u, const float* __restrict__ cvec, float* __restrict__ w)
{
    __shared__ float part[8][NHEADS][64];   // 24 KB
    __shared__ float scores[NHEADS][64];    // 3 KB
    __shared__ float attn_t[64][17];        // 4.25 KB (pad 17 -> conflict-free writes)

    const int bi   = blockIdx.x;
    const int t    = threadIdx.x;
    const int lane = t & 63;
    const int mc   = t >> 6;                // wave id = m-chunk (0..7)
    const int jl   = lane & 15;
    const int ms   = lane >> 4;             // 0..3 m-subchunk
    const size_t kvbase = (size_t)bi * 64 * DMODEL;
    const int mbase = mc * 96 + ms * 24;

    // ---- phase 1: partial scores. thread: rows {jl+16*rr}, m in [mbase, mbase+24)
    {
        float acc[NHEADS][4];
        #pragma unroll
        for (int h = 0; h < NHEADS; ++h)
            #pragma unroll
            for (int rr = 0; rr < 4; ++rr) acc[h][rr] = 0.f;

        const float* kp = key + kvbase + (size_t)jl * DMODEL + mbase;
        const float* up = u + (size_t)bi * BIW + mbase;
        #pragma unroll
        for (int mi = 0; mi < 6; ++mi) {
            float4 ka[4];
            #pragma unroll
            for (int rr = 0; rr < 4; ++rr)
                ka[rr] = *(const float4*)(kp + (size_t)rr * 16 * DMODEL + mi * 4);
            #pragma unroll
            for (int h = 0; h < NHEADS; ++h) {
                float4 uu = *(const float4*)(up + h * DMODEL + mi * 4);   // wave-uniform-ish broadcast
                #pragma unroll
                for (int rr = 0; rr < 4; ++rr)
                    acc[h][rr] += ka[rr].x * uu.x + ka[rr].y * uu.y + ka[rr].z * uu.z + ka[rr].w * uu.w;
            }
        }
        // reduce across ms (lanes ^16, ^32), then ms==0 writes
        #pragma unroll
        for (int h = 0; h < NHEADS; ++h)
            #pragma unroll
            for (int rr = 0; rr < 4; ++rr) {
                float v = acc[h][rr];
                v += __shfl_xor(v, 16);
                v += __shfl_xor(v, 32);
                acc[h][rr] = v;
            }
        if (ms == 0) {
            #pragma unroll
            for (int h = 0; h < NHEADS; ++h)
                #pragma unroll
                for (int rr = 0; rr < 4; ++rr)
                    part[mc][h][rr * 16 + jl] = acc[h][rr];
        }
    }
    __syncthreads();

    // ---- reduce partials + bias-dot + mask
    for (int p = t; p < NHEADS * 64; p += 512) {
        int h = p >> 6, j = p & 63;
        float s = 0.f;
        #pragma unroll
        for (int m8 = 0; m8 < 8; ++m8) s += part[m8][h][j];
        s += cvec[bi * NHEADS + h];
        s *= mask[bi * 64 + j];
        scores[h][j] = s;
    }
    __syncthreads();

    // ---- softmax over j per head: wave mc handles h = mc and mc+8 (if <12)
    {
        #pragma unroll
        for (int hh = 0; hh < 2; ++hh) {
            const int h = mc + hh * 8;
            if (h < NHEADS) {
                float s = scores[h][lane];
                float mx = s;
                #pragma unroll
                for (int o = 1; o < 64; o <<= 1) mx = fmaxf(mx, __shfl_xor(mx, o));
                float e = __expf(s - mx);
                float sm = e;
                #pragma unroll
                for (int o = 1; o < 64; o <<= 1) sm += __shfl_xor(sm, o);
                attn_t[lane][h] = e / sm;
            }
        }
    }
    __syncthreads();

    // ---- phase 3: two half-blocks of 256 threads; half hb owns heads hb*6..+6.
    //      thread owns m = mo + {0,256,512}; loops all 64 j (coalesced value reads)
    {
        const int hb = t >> 8, mo = t & 255;
        float a3[6][3];
        #pragma unroll
        for (int hh = 0; hh < 6; ++hh) { a3[hh][0] = 0.f; a3[hh][1] = 0.f; a3[hh][2] = 0.f; }
        const float* vb = value + kvbase + mo;
        for (int j = 0; j < 64; ++j) {
            float av[6];
            #pragma unroll
            for (int hh = 0; hh < 6; ++hh) av[hh] = attn_t[j][hb * 6 + hh];
            float v0 = vb[(size_t)j * DMODEL];
            float v1 = vb[(size_t)j * DMODEL + 256];
            float v2 = vb[(size_t)j * DMODEL + 512];
            #pragma unroll
            for (int hh = 0; hh < 6; ++hh) {
                a3[hh][0] += av[hh] * v0;
                a3[hh][1] += av[hh] * v1;
                a3[hh][2] += av[hh] * v2;
            }
        }
        #pragma unroll
        for (int hh = 0; hh < 6; ++hh)
            #pragma unroll
            for (int mm = 0; mm < 3; ++mm)
                w[(size_t)bi * BIW + (hb * 6 + hh) * DMODEL + mo + mm * 256] = a3[hh][mm];
    }
}

// ---------------------------------------------------------------------------
extern "C" void kernel_launch(void* const* d_in, const int* in_sizes, int n_in,
                              void* d_out, int out_size, void* d_ws, size_t ws_size,
                              hipStream_t stream) {
    const float* key   = (const float*)d_in[0];
    const float* value = (const float*)d_in[1];
    const float* query = (const float*)d_in[2];
    const float* mask  = (const float*)d_in[3];
    const float* Wk    = (const float*)d_in[4];
    const float* bk    = (const float*)d_in[5];
    const float* Wv    = (const float*)d_in[6];
    const float* bv    = (const float*)d_in[7];
    const float* Wq    = (const float*)d_in[8];
    const float* bq    = (const float*)d_in[9];
    const float* Wo    = (const float*)d_in[10];
    const float* bo    = (const float*)d_in[11];
    float* out = (float*)d_out;

    float* wsf    = (float*)d_ws;
    float* qp_ctx = wsf;                                // 512*768 (Qp, later reused as ctx)
    float* u_w    = wsf + (size_t)RTOT * DMODEL;        // 512*9216 (u, later reused as w)
    float* cvec   = u_w + (size_t)RTOT * BIW;           // 512*12

    // 1. Qp = (query @ Wq + bq) / 8
    linear32<<<dim3(16, 24), 256, 0, stream>>>(query, DMODEL, 0, Wq, bq, qp_ctx, DMODEL, 0.125f);
    // 2. u[r,h,m], cvec[r,h]
    u_kernel<<<dim3(16, 12, 12), 256, 0, stream>>>(qp_ctx, Wk, bk, u_w, cvec);
    // 3. scores/softmax/w  (w overwrites u region; block bi reads u[bi] fully before writing w[bi])
    attn_core<<<512, 512, 0, stream>>>(key, value, mask, u_w, cvec, u_w);
    // 4. ctx[r, h*64+cc] = w[r,h,:] @ Wv[:, h*64+cc] + bv   (ctx overwrites Qp region)
    linear32<<<dim3(16, 24), 256, 0, stream>>>(u_w, BIW, DMODEL, Wv, bv, qp_ctx, DMODEL, 1.0f);
    // 5. out = ctx @ Wo + bo
    linear32<<<dim3(16, 24), 256, 0, stream>>>(qp_ctx, DMODEL, 0, Wo, bo, out, DMODEL, 1.0f);
}

// Round 3
// 252.153 us; speedup vs baseline: 1.2590x; 1.2590x over previous
//
#include <hip/hip_runtime.h>

// Problem constants: B=8, L=64, D=768, H=12, d=64
#define DMODEL 768
#define NHEADS 12
#define RTOT   512           // B*L rows
#define BIW    9216          // NHEADS*DMODEL (per-(b,i) u/w row)

// ---------------------------------------------------------------------------
// 32x32-tile fp32 GEMM, register-double-buffered K chunks of 64.
// dst[r, ct*32+c] = (sum_k src[r*ars + sk + k]*W[k, ct*32+c] + bias)*scale
// sk = ((ct*32)>>6)*scm selects per-head source slice when scm=768.
// grid = (16, 24), 256 threads
// ---------------------------------------------------------------------------
__global__ __launch_bounds__(256) void linear32(
    const float* __restrict__ src, int ars, int scm,
    const float* __restrict__ W, const float* __restrict__ bias,
    float* __restrict__ dst, int drs, float scale)
{
    __shared__ float At[32][64];   // 8 KB
    __shared__ float Bt[64][32];   // 8 KB
    const int rt = blockIdx.x, ct = blockIdx.y, t = threadIdx.x;
    const int sk = ((ct * 32) >> 6) * scm;
    const int c  = t & 31;
    const int rg = t >> 5;             // 8 groups x 4 rows

    // staging coords (2 float4 per thread per operand)
    const int ar0 = t >> 4,          ak0 = t & 15;
    const int ar1 = (t + 256) >> 4,  ak1 = (t + 256) & 15;
    const int bk0 = t >> 3,          bc0 = (t & 7) * 4;
    const int bk1 = (t + 256) >> 3,  bc1 = ((t + 256) & 7) * 4;

    float4 va0, va1, vb0, vb1;
    auto LD = [&](int kb) {
        va0 = *(const float4*)&src[(size_t)(rt * 32 + ar0) * ars + sk + kb * 64 + ak0 * 4];
        va1 = *(const float4*)&src[(size_t)(rt * 32 + ar1) * ars + sk + kb * 64 + ak1 * 4];
        vb0 = *(const float4*)&W[(size_t)(kb * 64 + bk0) * DMODEL + ct * 32 + bc0];
        vb1 = *(const float4*)&W[(size_t)(kb * 64 + bk1) * DMODEL + ct * 32 + bc1];
    };

    LD(0);
    float acc[4] = {0.f, 0.f, 0.f, 0.f};

    for (int kb = 0; kb < 12; ++kb) {
        if (kb) __syncthreads();
        *(float4*)&At[ar0][ak0 * 4] = va0;
        *(float4*)&At[ar1][ak1 * 4] = va1;
        *(float4*)&Bt[bk0][bc0] = vb0;
        *(float4*)&Bt[bk1][bc1] = vb1;
        __syncthreads();
        if (kb < 11) LD(kb + 1);
        #pragma unroll
        for (int kq = 0; kq < 16; ++kq) {
            float b0 = Bt[kq * 4 + 0][c], b1 = Bt[kq * 4 + 1][c];
            float b2 = Bt[kq * 4 + 2][c], b3 = Bt[kq * 4 + 3][c];
            #pragma unroll
            for (int i = 0; i < 4; ++i) {
                float4 a = *(const float4*)&At[rg * 4 + i][kq * 4];
                acc[i] += a.x * b0 + a.y * b1 + a.z * b2 + a.w * b3;
            }
        }
    }
    const float bb = bias[ct * 32 + c];
    #pragma unroll
    for (int i = 0; i < 4; ++i)
        dst[(size_t)(rt * 32 + rg * 4 + i) * drs + ct * 32 + c] = (acc[i] + bb) * scale;
}

// ---------------------------------------------------------------------------
// u[r, h, m] = sum_d Qp[r, h*64+d] * Wk[m, h*64+d];  cvec[r,h] = sum_d bk[h*64+d]*Qp[r,h*64+d]
// grid = (16, 12, 12), 256 threads
// ---------------------------------------------------------------------------
__global__ __launch_bounds__(256) void u_kernel(
    const float* __restrict__ qp, const float* __restrict__ Wk, const float* __restrict__ bk,
    float* __restrict__ u, float* __restrict__ cvec)
{
    __shared__ float Qt[32][64];    // 8 KB
    __shared__ float Bt[64][65];    // 16.25 KB (pad -> conflict-free b32 row reads)
    const int rt = blockIdx.x, mt = blockIdx.y, h = blockIdx.z, t = threadIdx.x;

    #pragma unroll
    for (int kk = 0; kk < 2; ++kk) {
        int i4 = t + kk * 256;
        int r = i4 >> 4, dq = i4 & 15;
        *(float4*)&Qt[r][dq * 4] =
            *(const float4*)&qp[(size_t)(rt * 32 + r) * DMODEL + h * 64 + dq * 4];
    }
    #pragma unroll
    for (int kk = 0; kk < 4; ++kk) {
        int i4 = t + kk * 256;
        int m = i4 >> 4, dq = i4 & 15;
        float4 v = *(const float4*)&Wk[(size_t)(mt * 64 + m) * DMODEL + h * 64 + dq * 4];
        Bt[m][dq * 4 + 0] = v.x; Bt[m][dq * 4 + 1] = v.y;
        Bt[m][dq * 4 + 2] = v.z; Bt[m][dq * 4 + 3] = v.w;
    }
    __syncthreads();

    const int c = t & 63, rg = t >> 6;
    float acc[8] = {0.f,0.f,0.f,0.f,0.f,0.f,0.f,0.f};
    #pragma unroll
    for (int dq = 0; dq < 16; ++dq) {
        float b0 = Bt[c][dq * 4 + 0], b1 = Bt[c][dq * 4 + 1];
        float b2 = Bt[c][dq * 4 + 2], b3 = Bt[c][dq * 4 + 3];
        #pragma unroll
        for (int i = 0; i < 8; ++i) {
            float4 a = *(const float4*)&Qt[rg * 8 + i][dq * 4];
            acc[i] += a.x * b0 + a.y * b1 + a.z * b2 + a.w * b3;
        }
    }
    #pragma unroll
    for (int i = 0; i < 8; ++i)
        u[(size_t)(rt * 32 + rg * 8 + i) * BIW + h * DMODEL + mt * 64 + c] = acc[i];

    if (mt == 0 && t < 32) {
        float s = 0.f;
        for (int d = 0; d < 64; ++d) s += bk[h * 64 + d] * Qt[t][d];
        cvec[(rt * 32 + t) * NHEADS + h] = s;
    }
}

// ---------------------------------------------------------------------------
// Core: per (b,i) block, 512 threads (8 waves).
// Phase 1: coalesced key stream (m across lanes) + u in LDS + 30-shfl split-tree
//          reduction producing scores[12][64].
// Softmax per head on one wave. Phase 3: attn^T * value, coalesced.
// ---------------------------------------------------------------------------
__global__ __launch_bounds__(512, 4) void attn_core(
    const float* __restrict__ key, const float* __restrict__ value, const float* __restrict__ mask,
    const float* __restrict__ u, const float* __restrict__ cvec, float* __restrict__ w)
{
    __shared__ float u_sh[NHEADS * DMODEL];   // 36 KB
    __shared__ float sc[NHEADS][66];          // scores -> attn in place (pad 66)

    const int bi   = blockIdx.x;
    const int t    = threadIdx.x;
    const int lane = t & 63;
    const int wv   = t >> 6;                  // wave 0..7
    const size_t kvb = (size_t)bi * 64 * DMODEL;

    // stage u[bi] (36 KB), coalesced
    #pragma unroll
    for (int kk = 0; kk < 5; ++kk) {
        int idx = (t + kk * 512) * 4;
        if (idx < NHEADS * DMODEL)
            *(float4*)&u_sh[idx] = *(const float4*)&u[(size_t)bi * BIW + idx];
    }
    __syncthreads();

    // ---- phase 1: wave wv owns rows j = wv*8 .. wv*8+7, 4 rows per sub-iter
    #pragma unroll
    for (int rb = 0; rb < 2; ++rb) {
        const int j0 = wv * 8 + rb * 4;
        float a[NHEADS][4];
        #pragma unroll
        for (int h = 0; h < NHEADS; ++h)
            #pragma unroll
            for (int r = 0; r < 4; ++r) a[h][r] = 0.f;

        #pragma unroll
        for (int cch = 0; cch < 3; ++cch) {
            float4 k4[4];
            #pragma unroll
            for (int r = 0; r < 4; ++r)
                k4[r] = *(const float4*)&key[kvb + (size_t)(j0 + r) * DMODEL + cch * 256 + lane * 4];
            #pragma unroll
            for (int h = 0; h < NHEADS; ++h) {
                float4 u4 = *(const float4*)&u_sh[h * DMODEL + cch * 256 + lane * 4];
                #pragma unroll
                for (int r = 0; r < 4; ++r)
                    a[h][r] += k4[r].x * u4.x + k4[r].y * u4.y + k4[r].z * u4.z + k4[r].w * u4.w;
            }
        }
        // split-tree reduce: 12 heads over 64 lanes -> 30 shfl per row
        #pragma unroll
        for (int r = 0; r < 4; ++r) {
            float s6[6];
            #pragma unroll
            for (int i = 0; i < 6; ++i) {
                float lo = a[i][r], hi = a[i + 6][r];
                float tl = __shfl_xor(lo, 32), th = __shfl_xor(hi, 32);
                s6[i] = (lane < 32) ? lo + tl : hi + th;
            }
            float s3[3];
            #pragma unroll
            for (int i = 0; i < 3; ++i) {
                float lo = s6[i], hi = s6[i + 3];
                float tl = __shfl_xor(lo, 16), th = __shfl_xor(hi, 16);
                s3[i] = ((lane & 16) == 0) ? lo + tl : hi + th;
            }
            #pragma unroll
            for (int o = 8; o >= 1; o >>= 1)
                #pragma unroll
                for (int i = 0; i < 3; ++i) s3[i] += __shfl_xor(s3[i], o);
            if ((lane & 15) == 0) {
                const int g = lane >> 4;
                #pragma unroll
                for (int i = 0; i < 3; ++i) sc[g * 3 + i][j0 + r] = s3[i];
            }
        }
    }
    __syncthreads();

    // ---- softmax: wave wv -> head wv; waves 0..3 also head 8+wv
    {
        const float mk = mask[bi * 64 + lane];
        #pragma unroll
        for (int hh = 0; hh < 2; ++hh) {
            const int h = wv + hh * 8;
            if (h < NHEADS) {
                float s = (sc[h][lane] + cvec[bi * NHEADS + h]) * mk;
                float mx = s;
                #pragma unroll
                for (int o = 1; o < 64; o <<= 1) mx = fmaxf(mx, __shfl_xor(mx, o));
                float e = __expf(s - mx);
                float sm = e;
                #pragma unroll
                for (int o = 1; o < 64; o <<= 1) sm += __shfl_xor(sm, o);
                sc[h][lane] = e / sm;
            }
        }
    }
    __syncthreads();

    // ---- phase 3: halves of 256 threads; half hb owns heads hb*6..+6;
    //      thread owns m = mo + {0,256,512}; coalesced value reads
    {
        const int hb = t >> 8, mo = t & 255;
        float a3[6][3];
        #pragma unroll
        for (int hh = 0; hh < 6; ++hh) { a3[hh][0] = 0.f; a3[hh][1] = 0.f; a3[hh][2] = 0.f; }
        const float* vb = value + kvb + mo;
        #pragma unroll 4
        for (int j = 0; j < 64; ++j) {
            float v0 = vb[(size_t)j * DMODEL];
            float v1 = vb[(size_t)j * DMODEL + 256];
            float v2 = vb[(size_t)j * DMODEL + 512];
            #pragma unroll
            for (int hh = 0; hh < 6; ++hh) {
                float av = sc[hb * 6 + hh][j];
                a3[hh][0] += av * v0;
                a3[hh][1] += av * v1;
                a3[hh][2] += av * v2;
            }
        }
        #pragma unroll
        for (int hh = 0; hh < 6; ++hh)
            #pragma unroll
            for (int mm = 0; mm < 3; ++mm)
                w[(size_t)bi * BIW + (hb * 6 + hh) * DMODEL + mo + mm * 256] = a3[hh][mm];
    }
}

// ---------------------------------------------------------------------------
extern "C" void kernel_launch(void* const* d_in, const int* in_sizes, int n_in,
                              void* d_out, int out_size, void* d_ws, size_t ws_size,
                              hipStream_t stream) {
    const float* key   = (const float*)d_in[0];
    const float* value = (const float*)d_in[1];
    const float* query = (const float*)d_in[2];
    const float* mask  = (const float*)d_in[3];
    const float* Wk    = (const float*)d_in[4];
    const float* bk    = (const float*)d_in[5];
    const float* Wv    = (const float*)d_in[6];
    const float* bv    = (const float*)d_in[7];
    const float* Wq    = (const float*)d_in[8];
    const float* bq    = (const float*)d_in[9];
    const float* Wo    = (const float*)d_in[10];
    const float* bo    = (const float*)d_in[11];
    float* out = (float*)d_out;

    float* wsf    = (float*)d_ws;
    float* qp_ctx = wsf;                                // 512*768 (Qp, later ctx)
    float* u_w    = wsf + (size_t)RTOT * DMODEL;        // 512*9216 (u, later w)
    float* cvec   = u_w + (size_t)RTOT * BIW;           // 512*12

    // 1. Qp = (query @ Wq + bq) / 8
    linear32<<<dim3(16, 24), 256, 0, stream>>>(query, DMODEL, 0, Wq, bq, qp_ctx, DMODEL, 0.125f);
    // 2. u[r,h,m], cvec[r,h]
    u_kernel<<<dim3(16, 12, 12), 256, 0, stream>>>(qp_ctx, Wk, bk, u_w, cvec);
    // 3. scores/softmax/w  (w overwrites u region; u staged to LDS before w writes)
    attn_core<<<512, 512, 0, stream>>>(key, value, mask, u_w, cvec, u_w);
    // 4. ctx[r, h*64+cc] = w[r,h,:] @ Wv[:, h*64+cc] + bv
    linear32<<<dim3(16, 24), 256, 0, stream>>>(u_w, BIW, DMODEL, Wv, bv, qp_ctx, DMODEL, 1.0f);
    // 5. out = ctx @ Wo + bo
    linear32<<<dim3(16, 24), 256, 0, stream>>>(qp_ctx, DMODEL, 0, Wo, bo, out, DMODEL, 1.0f);
}